// Round 6
// baseline (1064.568 us; speedup 1.0000x reference)
//
#include <hip/hip_runtime.h>
#include <hip/hip_bf16.h>

// B=128, T=512, I=128, H=256, O=1 (fp32 in/out)
// xp = (x @ W_ih^T + b_ih + b_hh) * C   (C = 2/ln2, pre-scaled for tanh; fp32 ws)
// h_t = tanh(xp_t + h @ W_hh^T)  via MFMA with W_hh pre-scaled by C
// out = sigmoid(h_T @ W_fc^T + b_fc)

#define B_ 128
#define T_ 512
#define I_ 128
#define H_ 256
#define HP 264   // padded LDS row stride (shorts): stride%32dw = 4 -> 2-way = free
#define CSCALE 2.8853900817779268f   // 2*log2(e)

typedef __attribute__((ext_vector_type(8))) short short8;
typedef __attribute__((ext_vector_type(4))) float floatx4;

// tanh with PRE-SCALED input x = 2*log2e*z:  tanh(z) = 1 - 2*rcp(2^x + 1)
__device__ __forceinline__ float tanh_pre(float x) {
    float e = __builtin_amdgcn_exp2f(x);
    float r = __builtin_amdgcn_rcpf(e + 1.0f);
    return __builtin_fmaf(-2.0f, r, 1.0f);
}

// RNE fp32->bf16, finite inputs only
__device__ __forceinline__ short f2bf(float f) {
    unsigned u = __float_as_uint(f);
    return (short)((u + 0x7FFFu + ((u >> 16) & 1u)) >> 16);
}
__device__ __forceinline__ unsigned rne_pack(float a, float b) {
    unsigned ua = __float_as_uint(a), ub = __float_as_uint(b);
    ua = (ua + 0x7FFFu + ((ua >> 16) & 1u)) >> 16;
    ub = (ub + 0x7FFFu + ((ub >> 16) & 1u));
    return (ub & 0xFFFF0000u) | ua;
}

// ---------------- Kernel A: xp[m][n] = C*(bias[n] + sum x*W) via bf16 MFMA.
// Tile 64m x 128n, 4 waves: wave&1 = m-half (2 mt), wave>>1 = n-half (4 nt).
// ~150 VGPR -> 2 blocks/CU for latency hiding.
__global__ __launch_bounds__(256, 2)
void xp_mfma_kernel(const float* __restrict__ x, const float* __restrict__ W_ih,
                    const float* __restrict__ b_ih, const float* __restrict__ b_hh,
                    float* __restrict__ xp) {
    const int tid  = threadIdx.x;
    const int wave = tid >> 6, lane = tid & 63;
    const int l15  = lane & 15, quad = lane >> 4;
    const long m0 = (long)blockIdx.x * 64 + (wave & 1) * 32;
    const int  n0 = blockIdx.y * 128 + (wave >> 1) * 64;

    // W_ih fragments (pre-scaled by C at conversion)
    short8 bfrag[4][4];
#pragma unroll
    for (int nt = 0; nt < 4; ++nt)
#pragma unroll
        for (int kq = 0; kq < 4; ++kq) {
            const float* p = W_ih + (long)(n0 + nt * 16 + l15) * I_ + kq * 32 + quad * 8;
            float4 lo = *(const float4*)(p);
            float4 hi = *(const float4*)(p + 4);
            short8 f;
            f[0] = f2bf(lo.x * CSCALE); f[1] = f2bf(lo.y * CSCALE);
            f[2] = f2bf(lo.z * CSCALE); f[3] = f2bf(lo.w * CSCALE);
            f[4] = f2bf(hi.x * CSCALE); f[5] = f2bf(hi.y * CSCALE);
            f[6] = f2bf(hi.z * CSCALE); f[7] = f2bf(hi.w * CSCALE);
            bfrag[nt][kq] = f;
        }

    short8 afrag[2][4];
#pragma unroll
    for (int mt = 0; mt < 2; ++mt)
#pragma unroll
        for (int kq = 0; kq < 4; ++kq) {
            const float* p = x + (m0 + mt * 16 + l15) * I_ + kq * 32 + quad * 8;
            float4 lo = *(const float4*)(p);
            float4 hi = *(const float4*)(p + 4);
            short8 f;
            f[0] = f2bf(lo.x); f[1] = f2bf(lo.y); f[2] = f2bf(lo.z); f[3] = f2bf(lo.w);
            f[4] = f2bf(hi.x); f[5] = f2bf(hi.y); f[6] = f2bf(hi.z); f[7] = f2bf(hi.w);
            afrag[mt][kq] = f;
        }

    floatx4 acc[2][4];
#pragma unroll
    for (int mt = 0; mt < 2; ++mt)
#pragma unroll
        for (int nt = 0; nt < 4; ++nt) acc[mt][nt] = (floatx4){0.f, 0.f, 0.f, 0.f};

#pragma unroll
    for (int kq = 0; kq < 4; ++kq)
#pragma unroll
        for (int mt = 0; mt < 2; ++mt)
#pragma unroll
            for (int nt = 0; nt < 4; ++nt)
                acc[mt][nt] = __builtin_amdgcn_mfma_f32_16x16x32_bf16(
                    afrag[mt][kq], bfrag[nt][kq], acc[mt][nt], 0, 0, 0);

    float biasv[4];
#pragma unroll
    for (int nt = 0; nt < 4; ++nt) {
        int n = n0 + nt * 16 + l15;
        biasv[nt] = (b_ih[n] + b_hh[n]) * CSCALE;
    }
#pragma unroll
    for (int mt = 0; mt < 2; ++mt)
#pragma unroll
        for (int nt = 0; nt < 4; ++nt)
#pragma unroll
            for (int r = 0; r < 4; ++r) {
                long row = m0 + mt * 16 + quad * 4 + r;
                xp[row * H_ + n0 + nt * 16 + l15] = acc[mt][nt][r] + biasv[nt];
            }
}

// ---------------- Kernel B: MFMA recurrence, 8 blocks x 16 batches x 128 thr.
// 2 waves/block, each wave owns 128 n-cols (mt=8) -> h-read duplication halved
// vs 4-wave split. W_hh fragments: 8x8 short8 = 256 VGPR/thread, resident.
// acc init = pre-scaled xp (C-layout == xp layout); tanh input needs no mul.
__global__ __launch_bounds__(128, 1)
void rnn_kernel(const float* __restrict__ xp, const float* __restrict__ W_hh,
                const float* __restrict__ W_fc, const float* __restrict__ b_fc,
                float* __restrict__ out) {
    __shared__ __align__(16) short hbuf[2][16][HP];
    const int tid  = threadIdx.x;
    const int wave = tid >> 6, lane = tid & 63;
    const int l15  = lane & 15, quad = lane >> 4;
    const int b0   = blockIdx.x * 16;
    const int n0w  = wave * 128;

    // W_hh A-fragments, pre-scaled by C, resident across all 512 steps
    short8 wfrag[8][8];
#pragma unroll
    for (int mt = 0; mt < 8; ++mt)
#pragma unroll
        for (int kq = 0; kq < 8; ++kq) {
            const float* p = W_hh + (long)(n0w + mt * 16 + l15) * H_ + kq * 32 + quad * 8;
            float4 lo = *(const float4*)(p);
            float4 hi = *(const float4*)(p + 4);
            short8 f;
            f[0] = f2bf(lo.x * CSCALE); f[1] = f2bf(lo.y * CSCALE);
            f[2] = f2bf(lo.z * CSCALE); f[3] = f2bf(lo.w * CSCALE);
            f[4] = f2bf(hi.x * CSCALE); f[5] = f2bf(hi.y * CSCALE);
            f[6] = f2bf(hi.z * CSCALE); f[7] = f2bf(hi.w * CSCALE);
            wfrag[mt][kq] = f;
        }

    {   // h_0 = 0 (both parities)
        int* hz = (int*)hbuf;
#pragma unroll 1
        for (int i = tid; i < (int)(sizeof(hbuf) / 4); i += 128) hz[i] = 0;
    }
    __syncthreads();

    const float* xpl = xp + (long)(b0 + l15) * T_ * H_ + n0w + quad * 4;
    float4 xv[8];
#pragma unroll
    for (int mt = 0; mt < 8; ++mt) xv[mt] = *(const float4*)(xpl + mt * 16);

    const int laneoff = l15 * HP + quad * 8;

#pragma unroll 1
    for (int t = 0; t < T_; ++t) {
        // consume xv into acc, then immediately refill xv for t+1 (covered by
        // this step's MFMA+epilogue; vmcnt wait lands at next acc-init)
        floatx4 acc[8];
#pragma unroll
        for (int mt = 0; mt < 8; ++mt) {
            acc[mt][0] = xv[mt].x; acc[mt][1] = xv[mt].y;
            acc[mt][2] = xv[mt].z; acc[mt][3] = xv[mt].w;
        }
        const long tn = (t + 1 < T_) ? (t + 1) : (T_ - 1);
#pragma unroll
        for (int mt = 0; mt < 8; ++mt)
            xv[mt] = *(const float4*)(xpl + tn * H_ + mt * 16);

        const short* hb = &hbuf[t & 1][0][0];
        short8 hfrag[8];
#pragma unroll
        for (int kq = 0; kq < 8; ++kq)
            hfrag[kq] = *(const short8*)(hb + laneoff + kq * 32);

#pragma unroll
        for (int kq = 0; kq < 8; ++kq)
#pragma unroll
            for (int mt = 0; mt < 8; ++mt)
                acc[mt] = __builtin_amdgcn_mfma_f32_16x16x32_bf16(
                    wfrag[mt][kq], hfrag[kq], acc[mt], 0, 0, 0);

        short* wb = &hbuf[(t + 1) & 1][0][0];
#pragma unroll
        for (int mt = 0; mt < 8; ++mt) {
            float y0 = tanh_pre(acc[mt][0]);
            float y1 = tanh_pre(acc[mt][1]);
            float y2 = tanh_pre(acc[mt][2]);
            float y3 = tanh_pre(acc[mt][3]);
            uint2 pk;
            pk.x = rne_pack(y0, y1);
            pk.y = rne_pack(y2, y3);
            *(uint2*)(wb + l15 * HP + n0w + mt * 16 + quad * 4) = pk;
        }
        __syncthreads();
    }

    // head: out[b] = sigmoid(b_fc + sum_n h_T[b][n]*W_fc[n]); h_T at parity 0
    const int bl = tid >> 3, seg = tid & 7;    // 16 batches x 8 lanes x 32 elems
    const short* hr = &hbuf[0][bl][seg * 32];
    float p = 0.0f;
#pragma unroll
    for (int i = 0; i < 32; ++i) {
        unsigned u = (unsigned)(unsigned short)hr[i];
        p += __uint_as_float(u << 16) * W_fc[seg * 32 + i];
    }
#pragma unroll
    for (int off = 1; off < 8; off <<= 1) p += __shfl_xor(p, off);
    if (seg == 0) out[b0 + bl] = 1.0f / (1.0f + __expf(-(p + b_fc[0])));
}

extern "C" void kernel_launch(void* const* d_in, const int* in_sizes, int n_in,
                              void* d_out, int out_size, void* d_ws, size_t ws_size,
                              hipStream_t stream) {
    const float* x    = (const float*)d_in[0];
    const float* W_ih = (const float*)d_in[1];
    const float* W_hh = (const float*)d_in[2];
    const float* b_ih = (const float*)d_in[3];
    const float* b_hh = (const float*)d_in[4];
    const float* W_fc = (const float*)d_in[5];
    const float* b_fc = (const float*)d_in[6];
    float* out = (float*)d_out;

    float* xp = (float*)d_ws;   // B*T*H fp32 = 67.1 MB

    dim3 gridA((B_ * T_) / 64, H_ / 128);
    xp_mfma_kernel<<<gridA, 256, 0, stream>>>(x, W_ih, b_ih, b_hh, xp);
    rnn_kernel<<<B_ / 16, 128, 0, stream>>>(xp, W_hh, W_fc, b_fc, out);
}

// Round 7
// 850.640 us; speedup vs baseline: 1.2515x; 1.2515x over previous
//
#include <hip/hip_runtime.h>
#include <hip/hip_bf16.h>

// B=128, T=512, I=128, H=256, O=1 (fp32 in/out)
// xp = C*(x @ W_ih^T + b_ih + b_hh)   (C = 2*log2e, pre-scaled for tanh; fp32 ws)
// h_t = tanh(xp_t + h @ W_hh^T)  via MFMA, W_hh pre-scaled by C at frag load
// out = sigmoid(h_T @ W_fc^T + b_fc)
// FUSED: producer blocks fill xp in t-chunk order; 4 rnn blocks consume behind
// device-scope flags (G16 pattern: threadfence+atomicAdd / spin+threadfence).

#define B_ 128
#define T_ 512
#define I_ 128
#define H_ 256
#define HP 264   // padded LDS row stride (shorts)
#define CSCALE 2.8853900817779268f
#define NRNN 4
#define NPROD 1024           // 8 t-chunks x 128 b-blocks
#define CHUNK_TARGET 128u

typedef __attribute__((ext_vector_type(8))) short short8;
typedef __attribute__((ext_vector_type(4))) float floatx4;

// tanh with PRE-SCALED input x = 2*log2e*z: tanh(z) = 1 - 2*rcp(2^x + 1)
__device__ __forceinline__ float tanh_pre(float x) {
    float e = __builtin_amdgcn_exp2f(x);
    float r = __builtin_amdgcn_rcpf(e + 1.0f);
    return __builtin_fmaf(-2.0f, r, 1.0f);
}
__device__ __forceinline__ short f2bf(float f) {
    unsigned u = __float_as_uint(f);
    return (short)((u + 0x7FFFu + ((u >> 16) & 1u)) >> 16);
}
__device__ __forceinline__ unsigned rne_pack(float a, float b) {
    unsigned ua = __float_as_uint(a), ub = __float_as_uint(b);
    ua = (ua + 0x7FFFu + ((ua >> 16) & 1u)) >> 16;
    ub = (ub + 0x7FFFu + ((ub >> 16) & 1u));
    return (ub & 0xFFFF0000u) | ua;
}

// ---------------- W_ih -> bf16, pre-scaled by C (runs once, 64 KB in ws)
__global__ void wcvt_kernel(const float* __restrict__ W, unsigned short* __restrict__ wb) {
    int i = blockIdx.x * 256 + threadIdx.x;
    if (i < H_ * I_) wb[i] = (unsigned short)f2bf(W[i] * CSCALE);
}

__device__ __forceinline__ void wait_chunk(unsigned* flags, int tc) {
    if (threadIdx.x == 0) {
        while (__hip_atomic_load(&flags[tc], __ATOMIC_RELAXED, __HIP_MEMORY_SCOPE_AGENT)
               < CHUNK_TARGET)
            __builtin_amdgcn_s_sleep(4);
        __threadfence();   // acquire: make producers' xp stores visible
    }
    __syncthreads();
}

// ---------------- producer: one 64m x 256n xp tile (b, t-chunk ordered)
__device__ __forceinline__ void producer_body(
        int p, const float* __restrict__ x, const unsigned short* __restrict__ wb,
        const float* __restrict__ b_ih, const float* __restrict__ b_hh,
        float* xp, unsigned* flags) {
    const int tid  = threadIdx.x;
    const int wave = tid >> 6, lane = tid & 63;
    const int l15  = lane & 15, quad = lane >> 4;
    const int tc   = p >> 7, b = p & 127;
    const int msub = wave & 1;
    const int n0   = (wave >> 1) * 64;
    const long m0  = (long)b * T_ + tc * 64 + msub * 32;

    short8 bfrag[4][4];   // bf16 W_ih (pre-scaled), no cvt VALU
#pragma unroll
    for (int nt = 0; nt < 4; ++nt)
#pragma unroll
        for (int kq = 0; kq < 4; ++kq)
            bfrag[nt][kq] = *(const short8*)(wb + (long)(n0 + nt * 16 + l15) * I_ + kq * 32 + quad * 8);

    short8 afrag[2][4];
#pragma unroll
    for (int mt = 0; mt < 2; ++mt)
#pragma unroll
        for (int kq = 0; kq < 4; ++kq) {
            const float* pp = x + (m0 + mt * 16 + l15) * I_ + kq * 32 + quad * 8;
            float4 lo = *(const float4*)(pp);
            float4 hi = *(const float4*)(pp + 4);
            short8 f;
            f[0] = f2bf(lo.x); f[1] = f2bf(lo.y); f[2] = f2bf(lo.z); f[3] = f2bf(lo.w);
            f[4] = f2bf(hi.x); f[5] = f2bf(hi.y); f[6] = f2bf(hi.z); f[7] = f2bf(hi.w);
            afrag[mt][kq] = f;
        }

    floatx4 acc[2][4];
#pragma unroll
    for (int mt = 0; mt < 2; ++mt)
#pragma unroll
        for (int nt = 0; nt < 4; ++nt) acc[mt][nt] = (floatx4){0.f, 0.f, 0.f, 0.f};
#pragma unroll
    for (int kq = 0; kq < 4; ++kq)
#pragma unroll
        for (int mt = 0; mt < 2; ++mt)
#pragma unroll
            for (int nt = 0; nt < 4; ++nt)
                acc[mt][nt] = __builtin_amdgcn_mfma_f32_16x16x32_bf16(
                    afrag[mt][kq], bfrag[nt][kq], acc[mt][nt], 0, 0, 0);

    float biasv[4];
#pragma unroll
    for (int nt = 0; nt < 4; ++nt) {
        int n = n0 + nt * 16 + l15;
        biasv[nt] = (b_ih[n] + b_hh[n]) * CSCALE;
    }
#pragma unroll
    for (int mt = 0; mt < 2; ++mt)
#pragma unroll
        for (int nt = 0; nt < 4; ++nt)
#pragma unroll
            for (int r = 0; r < 4; ++r) {
                long row = m0 + mt * 16 + quad * 4 + r;
                xp[row * H_ + n0 + nt * 16 + l15] = acc[mt][nt][r] + biasv[nt];
            }

    __threadfence();      // drain this thread's xp stores to device scope
    __syncthreads();      // all threads of the block done
    if (tid == 0) atomicAdd(&flags[tc], 1u);
}

// ---------------- rnn: round-5 proven skeleton (mt=4, VGPR=128) + prescale
__device__ __forceinline__ void rnn_body(
        int rb, short* hb, const float* xp, const float* __restrict__ W_hh,
        const float* __restrict__ W_fc, const float* __restrict__ b_fc,
        float* __restrict__ out, unsigned* flags) {
    const int tid  = threadIdx.x;
    const int wave = tid >> 6, lane = tid & 63;
    const int l15  = lane & 15, quad = lane >> 4;
    const int g    = wave >> 2;          // batch-group 0/1
    const int n0   = (wave & 3) * 64;
    const int b0   = rb * 32;
    const int GSZ  = 16 * HP;            // one parity buffer (shorts)

    short8 wfrag[4][8];
#pragma unroll
    for (int mt = 0; mt < 4; ++mt)
#pragma unroll
        for (int kq = 0; kq < 8; ++kq) {
            const float* p = W_hh + (long)(n0 + mt * 16 + l15) * H_ + kq * 32 + quad * 8;
            float4 lo = *(const float4*)(p);
            float4 hi = *(const float4*)(p + 4);
            short8 f;
            f[0] = f2bf(lo.x * CSCALE); f[1] = f2bf(lo.y * CSCALE);
            f[2] = f2bf(lo.z * CSCALE); f[3] = f2bf(lo.w * CSCALE);
            f[4] = f2bf(hi.x * CSCALE); f[5] = f2bf(hi.y * CSCALE);
            f[6] = f2bf(hi.z * CSCALE); f[7] = f2bf(hi.w * CSCALE);
            wfrag[mt][kq] = f;
        }

    {   // h_0 = 0
        int* hz = (int*)hb;
#pragma unroll 1
        for (int i = tid; i < 2 * 2 * GSZ / 2; i += 512) hz[i] = 0;
    }
    __syncthreads();

    if (flags) wait_chunk(flags, 0);

    const float* xpl = xp + (long)(b0 + g * 16 + l15) * T_ * H_ + n0 + quad * 4;
    float4 xv[4];
#pragma unroll
    for (int mt = 0; mt < 4; ++mt) xv[mt] = *(const float4*)(xpl + mt * 16);

    const int laneoff = l15 * HP + quad * 8;
    const int gbase   = g * 2 * GSZ;

#pragma unroll 2
    for (int t = 0; t < T_; ++t) {
        floatx4 acc[4];
#pragma unroll
        for (int mt = 0; mt < 4; ++mt) {
            acc[mt][0] = xv[mt].x; acc[mt][1] = xv[mt].y;
            acc[mt][2] = xv[mt].z; acc[mt][3] = xv[mt].w;
        }
        const long tn = (t + 1 < T_) ? (t + 1) : (T_ - 1);
        if (flags && ((t + 1) & 63) == 0 && (t + 1) < T_)
            wait_chunk(flags, (t + 1) >> 6);
#pragma unroll
        for (int mt = 0; mt < 4; ++mt)
            xv[mt] = *(const float4*)(xpl + tn * H_ + mt * 16);

        const short* hbr = hb + gbase + (t & 1) * GSZ;
        short8 hfrag[8];
#pragma unroll
        for (int kq = 0; kq < 8; ++kq)
            hfrag[kq] = *(const short8*)(hbr + laneoff + kq * 32);

#pragma unroll
        for (int kq = 0; kq < 8; ++kq)
#pragma unroll
            for (int mt = 0; mt < 4; ++mt)
                acc[mt] = __builtin_amdgcn_mfma_f32_16x16x32_bf16(
                    wfrag[mt][kq], hfrag[kq], acc[mt], 0, 0, 0);

        short* wbp = hb + gbase + ((t + 1) & 1) * GSZ;
#pragma unroll
        for (int mt = 0; mt < 4; ++mt) {
            float y0 = tanh_pre(acc[mt][0]);
            float y1 = tanh_pre(acc[mt][1]);
            float y2 = tanh_pre(acc[mt][2]);
            float y3 = tanh_pre(acc[mt][3]);
            uint2 pk;
            pk.x = rne_pack(y0, y1);
            pk.y = rne_pack(y2, y3);
            *(uint2*)(wbp + l15 * HP + n0 + mt * 16 + quad * 4) = pk;
        }
        __syncthreads();
    }

    // head: out[b] = sigmoid(b_fc + sum_n h_T[b][n]*W_fc[n]); h_T at parity 0
    const int bl = tid >> 4, seg = tid & 15;
    const short* hr = hb + (bl >> 4) * 2 * GSZ + (bl & 15) * HP + seg * 16;
    float p = 0.0f;
#pragma unroll
    for (int i = 0; i < 16; ++i) {
        unsigned u = (unsigned)(unsigned short)hr[i];
        p += __uint_as_float(u << 16) * W_fc[seg * 16 + i];
    }
#pragma unroll
    for (int off = 1; off < 16; off <<= 1) p += __shfl_xor(p, off);
    if (seg == 0) out[b0 + bl] = 1.0f / (1.0f + __expf(-(p + b_fc[0])));
}

// ---------------- fused dispatcher: blocks 0..3 rnn (dispatched first, grab
// their CUs immediately), 4.. producers in t-chunk-major order.
__global__ __launch_bounds__(512, 2)
void fused_kernel(const float* __restrict__ x, const unsigned short* __restrict__ wb,
                  const float* __restrict__ b_ih, const float* __restrict__ b_hh,
                  const float* __restrict__ W_hh, const float* __restrict__ W_fc,
                  const float* __restrict__ b_fc, float* xp, unsigned* flags,
                  float* __restrict__ out) {
    __shared__ __align__(16) short hbuf[2 * 2 * 16 * HP];
    if (blockIdx.x < NRNN)
        rnn_body(blockIdx.x, hbuf, xp, W_hh, W_fc, b_fc, out, flags);
    else
        producer_body(blockIdx.x - NRNN, x, wb, b_ih, b_hh, xp, flags);
}

// ---------------- serial fallback (ws too small for wb+flags): round-6 A
__global__ __launch_bounds__(256, 2)
void xp_mfma_kernel(const float* __restrict__ x, const float* __restrict__ W_ih,
                    const float* __restrict__ b_ih, const float* __restrict__ b_hh,
                    float* __restrict__ xp) {
    const int tid  = threadIdx.x;
    const int wave = tid >> 6, lane = tid & 63;
    const int l15  = lane & 15, quad = lane >> 4;
    const long m0 = (long)blockIdx.x * 64 + (wave & 1) * 32;
    const int  n0 = blockIdx.y * 128 + (wave >> 1) * 64;

    short8 bfrag[4][4];
#pragma unroll
    for (int nt = 0; nt < 4; ++nt)
#pragma unroll
        for (int kq = 0; kq < 4; ++kq) {
            const float* p = W_ih + (long)(n0 + nt * 16 + l15) * I_ + kq * 32 + quad * 8;
            float4 lo = *(const float4*)(p);
            float4 hi = *(const float4*)(p + 4);
            short8 f;
            f[0] = f2bf(lo.x * CSCALE); f[1] = f2bf(lo.y * CSCALE);
            f[2] = f2bf(lo.z * CSCALE); f[3] = f2bf(lo.w * CSCALE);
            f[4] = f2bf(hi.x * CSCALE); f[5] = f2bf(hi.y * CSCALE);
            f[6] = f2bf(hi.z * CSCALE); f[7] = f2bf(hi.w * CSCALE);
            bfrag[nt][kq] = f;
        }
    short8 afrag[2][4];
#pragma unroll
    for (int mt = 0; mt < 2; ++mt)
#pragma unroll
        for (int kq = 0; kq < 4; ++kq) {
            const float* p = x + (m0 + mt * 16 + l15) * I_ + kq * 32 + quad * 8;
            float4 lo = *(const float4*)(p);
            float4 hi = *(const float4*)(p + 4);
            short8 f;
            f[0] = f2bf(lo.x); f[1] = f2bf(lo.y); f[2] = f2bf(lo.z); f[3] = f2bf(lo.w);
            f[4] = f2bf(hi.x); f[5] = f2bf(hi.y); f[6] = f2bf(hi.z); f[7] = f2bf(hi.w);
            afrag[mt][kq] = f;
        }
    floatx4 acc[2][4];
#pragma unroll
    for (int mt = 0; mt < 2; ++mt)
#pragma unroll
        for (int nt = 0; nt < 4; ++nt) acc[mt][nt] = (floatx4){0.f, 0.f, 0.f, 0.f};
#pragma unroll
    for (int kq = 0; kq < 4; ++kq)
#pragma unroll
        for (int mt = 0; mt < 2; ++mt)
#pragma unroll
            for (int nt = 0; nt < 4; ++nt)
                acc[mt][nt] = __builtin_amdgcn_mfma_f32_16x16x32_bf16(
                    afrag[mt][kq], bfrag[nt][kq], acc[mt][nt], 0, 0, 0);
    float biasv[4];
#pragma unroll
    for (int nt = 0; nt < 4; ++nt) {
        int n = n0 + nt * 16 + l15;
        biasv[nt] = (b_ih[n] + b_hh[n]) * CSCALE;
    }
#pragma unroll
    for (int mt = 0; mt < 2; ++mt)
#pragma unroll
        for (int nt = 0; nt < 4; ++nt)
#pragma unroll
            for (int r = 0; r < 4; ++r) {
                long row = m0 + mt * 16 + quad * 4 + r;
                xp[row * H_ + n0 + nt * 16 + l15] = acc[mt][nt][r] + biasv[nt];
            }
}

__global__ __launch_bounds__(512, 2)
void rnn_serial_kernel(const float* __restrict__ xp, const float* __restrict__ W_hh,
                       const float* __restrict__ W_fc, const float* __restrict__ b_fc,
                       float* __restrict__ out) {
    __shared__ __align__(16) short hbuf[2 * 2 * 16 * HP];
    rnn_body(blockIdx.x, hbuf, xp, W_hh, W_fc, b_fc, out, nullptr);
}

extern "C" void kernel_launch(void* const* d_in, const int* in_sizes, int n_in,
                              void* d_out, int out_size, void* d_ws, size_t ws_size,
                              hipStream_t stream) {
    const float* x    = (const float*)d_in[0];
    const float* W_ih = (const float*)d_in[1];
    const float* W_hh = (const float*)d_in[2];
    const float* b_ih = (const float*)d_in[3];
    const float* b_hh = (const float*)d_in[4];
    const float* W_fc = (const float*)d_in[5];
    const float* b_fc = (const float*)d_in[6];
    float* out = (float*)d_out;

    const size_t XPB = (size_t)B_ * T_ * H_ * sizeof(float);   // 67.1 MB
    float* xp = (float*)d_ws;

    if (ws_size >= XPB + 4096 + (size_t)H_ * I_ * 2) {
        unsigned*       flags = (unsigned*)((char*)d_ws + XPB);
        unsigned short* wbuf  = (unsigned short*)((char*)d_ws + XPB + 4096);
        hipMemsetAsync((void*)flags, 0, 4096, stream);
        wcvt_kernel<<<(H_ * I_ + 255) / 256, 256, 0, stream>>>(W_ih, wbuf);
        fused_kernel<<<NRNN + NPROD, 512, 0, stream>>>(
            x, wbuf, b_ih, b_hh, W_hh, W_fc, b_fc, xp, flags, out);
    } else {
        dim3 gridA((B_ * T_) / 64, H_ / 128);
        xp_mfma_kernel<<<gridA, 256, 0, stream>>>(x, W_ih, b_ih, b_hh, xp);
        rnn_serial_kernel<<<NRNN, 512, 0, stream>>>(xp, W_hh, W_fc, b_fc, out);
    }
}

// Round 8
// 785.529 us; speedup vs baseline: 1.3552x; 1.0829x over previous
//
#include <hip/hip_runtime.h>
#include <hip/hip_bf16.h>

// B=128, T=512, I=128, H=256, O=1 (fp32 in/out)
// xp = C*(x @ W_ih^T + b_ih + b_hh)   (C = 2*log2e, pre-scaled for tanh; fp32 ws)
// h_t = tanh(xp_t + h @ W_hh^T)  via MFMA, W_hh pre-scaled by C at frag load
// out = sigmoid(h_T @ W_fc^T + b_fc)

#define B_ 128
#define T_ 512
#define I_ 128
#define H_ 256
#define HP 264   // padded LDS row stride (shorts)
#define CSCALE 2.8853900817779268f

typedef __attribute__((ext_vector_type(8))) short short8;
typedef __attribute__((ext_vector_type(4))) float floatx4;

// tanh with PRE-SCALED input x = 2*log2e*z: tanh(z) = 1 - 2*rcp(2^x + 1)
__device__ __forceinline__ float tanh_pre(float x) {
    float e = __builtin_amdgcn_exp2f(x);
    float r = __builtin_amdgcn_rcpf(e + 1.0f);
    return __builtin_fmaf(-2.0f, r, 1.0f);
}
__device__ __forceinline__ short f2bf(float f) {
    unsigned u = __float_as_uint(f);
    return (short)((u + 0x7FFFu + ((u >> 16) & 1u)) >> 16);
}
// pack two fp32 -> bf16x2: round-to-nearest (ties away), 3 insts via v_perm
__device__ __forceinline__ unsigned rn_pack(float a, float b) {
    unsigned ua = __float_as_uint(a) + 0x8000u;
    unsigned ub = __float_as_uint(b) + 0x8000u;
    return __builtin_amdgcn_perm(ub, ua, 0x07060302u);  // [ub.hi16 : ua.hi16]
}

// ---------------- Kernel A: xp[m][n] = C*(bias + x@W^T), bf16 MFMA, fp32 out.
// Tile 64m x 128n, 4 waves, ~150 VGPR -> 2 blocks/CU. (round-5 proven)
__global__ __launch_bounds__(256, 2)
void xp_mfma_kernel(const float* __restrict__ x, const float* __restrict__ W_ih,
                    const float* __restrict__ b_ih, const float* __restrict__ b_hh,
                    float* __restrict__ xp) {
    const int tid  = threadIdx.x;
    const int wave = tid >> 6, lane = tid & 63;
    const int l15  = lane & 15, quad = lane >> 4;
    const long m0 = (long)blockIdx.x * 64 + (wave & 1) * 32;
    const int  n0 = blockIdx.y * 128 + (wave >> 1) * 64;

    short8 bfrag[4][4];
#pragma unroll
    for (int nt = 0; nt < 4; ++nt)
#pragma unroll
        for (int kq = 0; kq < 4; ++kq) {
            const float* p = W_ih + (long)(n0 + nt * 16 + l15) * I_ + kq * 32 + quad * 8;
            float4 lo = *(const float4*)(p);
            float4 hi = *(const float4*)(p + 4);
            short8 f;
            f[0] = f2bf(lo.x * CSCALE); f[1] = f2bf(lo.y * CSCALE);
            f[2] = f2bf(lo.z * CSCALE); f[3] = f2bf(lo.w * CSCALE);
            f[4] = f2bf(hi.x * CSCALE); f[5] = f2bf(hi.y * CSCALE);
            f[6] = f2bf(hi.z * CSCALE); f[7] = f2bf(hi.w * CSCALE);
            bfrag[nt][kq] = f;
        }
    short8 afrag[2][4];
#pragma unroll
    for (int mt = 0; mt < 2; ++mt)
#pragma unroll
        for (int kq = 0; kq < 4; ++kq) {
            const float* p = x + (m0 + mt * 16 + l15) * I_ + kq * 32 + quad * 8;
            float4 lo = *(const float4*)(p);
            float4 hi = *(const float4*)(p + 4);
            short8 f;
            f[0] = f2bf(lo.x); f[1] = f2bf(lo.y); f[2] = f2bf(lo.z); f[3] = f2bf(lo.w);
            f[4] = f2bf(hi.x); f[5] = f2bf(hi.y); f[6] = f2bf(hi.z); f[7] = f2bf(hi.w);
            afrag[mt][kq] = f;
        }
    floatx4 acc[2][4];
#pragma unroll
    for (int mt = 0; mt < 2; ++mt)
#pragma unroll
        for (int nt = 0; nt < 4; ++nt) acc[mt][nt] = (floatx4){0.f, 0.f, 0.f, 0.f};
#pragma unroll
    for (int kq = 0; kq < 4; ++kq)
#pragma unroll
        for (int mt = 0; mt < 2; ++mt)
#pragma unroll
            for (int nt = 0; nt < 4; ++nt)
                acc[mt][nt] = __builtin_amdgcn_mfma_f32_16x16x32_bf16(
                    afrag[mt][kq], bfrag[nt][kq], acc[mt][nt], 0, 0, 0);
    float biasv[4];
#pragma unroll
    for (int nt = 0; nt < 4; ++nt) {
        int n = n0 + nt * 16 + l15;
        biasv[nt] = (b_ih[n] + b_hh[n]) * CSCALE;
    }
#pragma unroll
    for (int mt = 0; mt < 2; ++mt)
#pragma unroll
        for (int nt = 0; nt < 4; ++nt)
#pragma unroll
            for (int r = 0; r < 4; ++r) {
                long row = m0 + mt * 16 + quad * 4 + r;
                xp[row * H_ + n0 + nt * 16 + l15] = acc[mt][nt][r] + biasv[nt];
            }
}

// ---------------- Kernel B: MFMA recurrence, 4 blocks x 32 batches x 512 thr.
// Critical-path repairs vs round 5:
//  - depth-2 xp prefetch ring (slack ~2 steps > 900cyc HBM latency)
//  - split accumulators: dependent-MFMA chain 8 -> 4 (+ one vector add)
//  - 3-inst v_perm bf16 pair-pack
__global__ __launch_bounds__(512, 2)
void rnn_kernel(const float* __restrict__ xp, const float* __restrict__ W_hh,
                const float* __restrict__ W_fc, const float* __restrict__ b_fc,
                float* __restrict__ out) {
    __shared__ __align__(16) short hbuf[2][2][16][HP];  // [group][parity][batch][col]
    const int tid  = threadIdx.x;
    const int wave = tid >> 6, lane = tid & 63;
    const int l15  = lane & 15, quad = lane >> 4;
    const int g    = wave >> 2;          // batch-group 0/1
    const int n0   = (wave & 3) * 64;
    const int b0   = blockIdx.x * 32;

    // W_hh A-fragments, pre-scaled by C, resident (128 VGPR — proven pattern)
    short8 wfrag[4][8];
#pragma unroll
    for (int mt = 0; mt < 4; ++mt)
#pragma unroll
        for (int kq = 0; kq < 8; ++kq) {
            const float* p = W_hh + (long)(n0 + mt * 16 + l15) * H_ + kq * 32 + quad * 8;
            float4 lo = *(const float4*)(p);
            float4 hi = *(const float4*)(p + 4);
            short8 f;
            f[0] = f2bf(lo.x * CSCALE); f[1] = f2bf(lo.y * CSCALE);
            f[2] = f2bf(lo.z * CSCALE); f[3] = f2bf(lo.w * CSCALE);
            f[4] = f2bf(hi.x * CSCALE); f[5] = f2bf(hi.y * CSCALE);
            f[6] = f2bf(hi.z * CSCALE); f[7] = f2bf(hi.w * CSCALE);
            wfrag[mt][kq] = f;
        }

    {   // h_0 = 0
        int* hz = (int*)hbuf;
#pragma unroll 1
        for (int i = tid; i < (int)(sizeof(hbuf) / 4); i += 512) hz[i] = 0;
    }
    __syncthreads();

    const float* xpl = xp + (long)(b0 + g * 16 + l15) * T_ * H_ + n0 + quad * 4;

    // prefetch ring: xv[t&1] holds xp_t; refilled with xp_{t+2}
    float4 xv[2][4];
#pragma unroll
    for (int mt = 0; mt < 4; ++mt) {
        xv[0][mt] = *(const float4*)(xpl + 0 * H_ + mt * 16);
        xv[1][mt] = *(const float4*)(xpl + 1 * H_ + mt * 16);
    }

    const int laneoff = l15 * HP + quad * 8;

#pragma unroll 2
    for (int t = 0; t < T_; ++t) {
        const int cur = t & 1;
        floatx4 accA[4], accB[4];
#pragma unroll
        for (int mt = 0; mt < 4; ++mt) {
            accA[mt][0] = xv[cur][mt].x; accA[mt][1] = xv[cur][mt].y;
            accA[mt][2] = xv[cur][mt].z; accA[mt][3] = xv[cur][mt].w;
            accB[mt] = (floatx4){0.f, 0.f, 0.f, 0.f};
        }
        // refill ring slot with xp_{t+2} (consumed 2 steps from now)
        const long tn = (t + 2 < T_) ? (t + 2) : (T_ - 1);
#pragma unroll
        for (int mt = 0; mt < 4; ++mt)
            xv[cur][mt] = *(const float4*)(xpl + tn * H_ + mt * 16);

        const short* hbr = &hbuf[g][t & 1][0][0];
        short8 hfrag[8];
#pragma unroll
        for (int kq = 0; kq < 8; ++kq)
            hfrag[kq] = *(const short8*)(hbr + laneoff + kq * 32);

#pragma unroll
        for (int kq = 0; kq < 4; ++kq)
#pragma unroll
            for (int mt = 0; mt < 4; ++mt)
                accA[mt] = __builtin_amdgcn_mfma_f32_16x16x32_bf16(
                    wfrag[mt][kq], hfrag[kq], accA[mt], 0, 0, 0);
#pragma unroll
        for (int kq = 4; kq < 8; ++kq)
#pragma unroll
            for (int mt = 0; mt < 4; ++mt)
                accB[mt] = __builtin_amdgcn_mfma_f32_16x16x32_bf16(
                    wfrag[mt][kq], hfrag[kq], accB[mt], 0, 0, 0);

        short* wbp = &hbuf[g][(t + 1) & 1][0][0];
#pragma unroll
        for (int mt = 0; mt < 4; ++mt) {
            floatx4 s = accA[mt] + accB[mt];
            float y0 = tanh_pre(s[0]);
            float y1 = tanh_pre(s[1]);
            float y2 = tanh_pre(s[2]);
            float y3 = tanh_pre(s[3]);
            uint2 pk;
            pk.x = rn_pack(y0, y1);
            pk.y = rn_pack(y2, y3);
            *(uint2*)(wbp + l15 * HP + n0 + mt * 16 + quad * 4) = pk;
        }
        __syncthreads();
    }

    // head: out[b] = sigmoid(b_fc + sum_n h_T[b][n]*W_fc[n]); h_T at parity 0
    const int bl = tid >> 4, seg = tid & 15;
    const short* hr = &hbuf[bl >> 4][0][bl & 15][seg * 16];
    float p = 0.0f;
#pragma unroll
    for (int i = 0; i < 16; ++i) {
        unsigned u = (unsigned)(unsigned short)hr[i];
        p += __uint_as_float(u << 16) * W_fc[seg * 16 + i];
    }
#pragma unroll
    for (int off = 1; off < 16; off <<= 1) p += __shfl_xor(p, off);
    if (seg == 0) out[b0 + bl] = 1.0f / (1.0f + __expf(-(p + b_fc[0])));
}

extern "C" void kernel_launch(void* const* d_in, const int* in_sizes, int n_in,
                              void* d_out, int out_size, void* d_ws, size_t ws_size,
                              hipStream_t stream) {
    const float* x    = (const float*)d_in[0];
    const float* W_ih = (const float*)d_in[1];
    const float* W_hh = (const float*)d_in[2];
    const float* b_ih = (const float*)d_in[3];
    const float* b_hh = (const float*)d_in[4];
    const float* W_fc = (const float*)d_in[5];
    const float* b_fc = (const float*)d_in[6];
    float* out = (float*)d_out;

    float* xp = (float*)d_ws;   // B*T*H fp32 = 67.1 MB

    dim3 gridA((B_ * T_) / 64, H_ / 128);
    xp_mfma_kernel<<<gridA, 256, 0, stream>>>(x, W_ih, b_ih, b_hh, xp);
    rnn_kernel<<<B_ / 32, 512, 0, stream>>>(xp, W_hh, W_fc, b_fc, out);
}